// Round 3
// baseline (410.297 us; speedup 1.0000x reference)
//
#include <hip/hip_runtime.h>

// CTC forward loss (sum, zero_infinity), B=32, T=1024, V=1024, L=256, S=513.
//
// Pass 1 (parallel): per (b,t) row, gather the 257 needed columns
//   (labels[b][0..255] and blank=0), exponentiate, and write compacted
//   IN-PLACE into cols 0..256 of the same row. One wave per row; the
//   __syncthreads barrier (which drains vmcnt(0) on gfx950) guarantees all
//   of the wave's scattered loads complete before the compacted stores.
//
// Pass 2 (sequential DP): one wave per batch item, states in registers
//   (lane l holds states 8l..8l+7, +state 512 on lane 63), linear-domain
//   recurrence with exact pow-2 rescaling every 8 steps. Emissions are now
//   ONE coalesced float4 load + one broadcast dword per step, no exps.

constexpr int B_ = 32, T_ = 1024, V_ = 1024, L_ = 256;
constexpr int S_ = 2 * L_ + 1;   // 513
constexpr int PF = 16;           // prefetch depth (time steps) in pass 2
constexpr float LN2F = 0.6931471805599453f;

__global__ __launch_bounds__(256, 4) void ctc_gather(
    float* __restrict__ lp, const int* __restrict__ labels)
{
    const int wave = threadIdx.x >> 6;
    const int lane = threadIdx.x & 63;
    const int r = blockIdx.x * 4 + wave;       // row index in [0, B*T)
    const int b = r >> 10;                     // T = 1024
    float* row = lp + (size_t)r * V_;
    const int* labb = labels + b * L_;

    const int4 e = *(const int4*)(labb + 4 * lane);
    const float v0 = row[e.x];
    const float v1 = row[e.y];
    const float v2 = row[e.z];
    const float v3 = row[e.w];
    const float vb = row[0];
    float4 q;
    q.x = __expf(v0); q.y = __expf(v1); q.z = __expf(v2); q.w = __expf(v3);
    const float qb = __expf(vb);
    __syncthreads();   // vmcnt(0) drain: all loads done before any store (in-place safety)
    *(float4*)(row + 4 * lane) = q;            // cols 4l..4l+3
    if (lane == 0) row[256] = qb;              // blank
}

__global__ __launch_bounds__(64, 1) void ctc_dp(
    const float* __restrict__ Q, const int* __restrict__ labels,
    const int* __restrict__ input_lens, const int* __restrict__ label_lens,
    float* __restrict__ out)
{
    __shared__ float Ls[S_];
    const int b    = blockIdx.x;
    const int lane = threadIdx.x;
    const float* Qb  = Q + (size_t)b * T_ * V_;
    const int*  labb = labels + b * L_;
    const int il = input_lens[b];
    const int ll = label_lens[b];
    const int tend = il < T_ ? il : T_;

    // lane l's label states: s = 8l+2m+1, label index 4l+m
    const int4 e  = *(const int4*)(labb + 4 * lane);
    const int  ep = (lane > 0) ? labb[4 * lane - 1] : -1;
    const float kf0 = ((8 * lane + 1) >= 3 && e.x != ep) ? 1.f : 0.f;
    const float kf1 = (e.y != e.x) ? 1.f : 0.f;
    const float kf2 = (e.z != e.y) ? 1.f : 0.f;
    const float kf3 = (e.w != e.z) ? 1.f : 0.f;

    // alpha at t=0 (linear domain; pass 1 already exponentiated)
    float p0 = 0.f, p1 = 0.f, p2 = 0.f, p3 = 0.f, p4 = 0.f,
          p5 = 0.f, p6 = 0.f, p7 = 0.f, p8 = 0.f;
    if (lane == 0) { p0 = Qb[256]; p1 = Qb[0]; }
    int Esc = 0;       // true alpha = stored * 2^{-Esc}

    // rolling prefetch of compacted rows, depth PF
    float4 f[PF]; float fb[PF];
    #pragma unroll
    for (int i = 0; i < PF; ++i) {
        int tp = 1 + i; if (tp > T_ - 1) tp = T_ - 1;
        const float* row = Qb + (size_t)tp * V_;
        f[i]  = *(const float4*)(row + 4 * lane);
        fb[i] = row[256];
    }

    float pm1 = 0.f;   // alpha[8l-1] for the upcoming step (p7 of lane-1); 0 at t=0

    auto rescale = [&]() {
        float m = fmaxf(fmaxf(fmaxf(fmaxf(p0, p1), fmaxf(p2, p3)),
                              fmaxf(fmaxf(p4, p5), fmaxf(p6, p7))), p8);
        #pragma unroll
        for (int off = 32; off >= 1; off >>= 1)
            m = fmaxf(m, __shfl_xor(m, off));
        const unsigned eb = (__float_as_uint(m) >> 23) & 0xffu;
        if (eb >= 1u && eb <= 253u) {
            const float sf = __uint_as_float((254u - eb) << 23);  // exact 2^(127-eb)
            p0 *= sf; p1 *= sf; p2 *= sf; p3 *= sf; p4 *= sf;
            p5 *= sf; p6 *= sf; p7 *= sf; p8 *= sf; pm1 *= sf;
            Esc += 127 - (int)eb;
        }
    };

    for (int t0 = 1; t0 < tend; t0 += 16) {
        #pragma unroll
        for (int i = 0; i < 16; ++i) {        // slot index == i (t0 ≡ 1 mod 16)
            const int t = t0 + i;
            const float4 q  = f[i];
            const float  qb = fb[i];
            int tp = t + PF; if (tp > T_ - 1) tp = T_ - 1;
            const float* row = Qb + (size_t)tp * V_;
            f[i]  = *(const float4*)(row + 4 * lane);
            fb[i] = row[256];

            if (t < tend) {                   // wave-uniform
                const float n0 = (p0 + pm1) * qb;
                const float n1 = fmaf(kf0, pm1, p1 + p0) * q.x;  // skip src = state 8l-1
                const float n2 = (p2 + p1) * qb;
                const float n3 = fmaf(kf1, p1, p3 + p2) * q.y;
                const float n4 = (p4 + p3) * qb;
                const float n5 = fmaf(kf2, p3, p5 + p4) * q.z;
                const float n6 = (p6 + p5) * qb;
                const float n7 = fmaf(kf3, p5, p7 + p6) * q.w;
                const float n8 = (p8 + p7) * qb;  // state 8l+8 (state 512 on lane 63)
                p0 = n0; p1 = n1; p2 = n2; p3 = n3; p4 = n4;
                p5 = n5; p6 = n6; p7 = n7; p8 = n8;
                pm1 = __shfl_up(p7, 1);           // for the next step
                if (lane == 0) pm1 = 0.f;
            }
            if (i == 7) rescale();
        }
        rescale();
    }

    // epilogue: pick states 2*ll and 2*ll-1 via LDS
    Ls[8 * lane + 0] = p0; Ls[8 * lane + 1] = p1;
    Ls[8 * lane + 2] = p2; Ls[8 * lane + 3] = p3;
    Ls[8 * lane + 4] = p4; Ls[8 * lane + 5] = p5;
    Ls[8 * lane + 6] = p6; Ls[8 * lane + 7] = p7;
    if (lane == 63) Ls[512] = p8;
    __syncthreads();
    if (lane == 0) {
        const int sl = 2 * ll;
        const float la  = Ls[sl];
        const float lb  = (sl >= 1) ? Ls[sl - 1] : 0.f;
        const float tot = la + lb;
        float loss = (float)Esc * LN2F - __logf(tot);
        if (!(loss <= 1e29f)) loss = 0.f;     // zero_infinity (tot==0 -> inf -> 0)
        atomicAdd(out, loss);
    }
}

extern "C" void kernel_launch(void* const* d_in, const int* in_sizes, int n_in,
                              void* d_out, int out_size, void* d_ws, size_t ws_size,
                              hipStream_t stream) {
    float*       lp     = (float*)d_in[0];    // mutated by pass 1; restored each replay
    const int*   labels = (const int*)d_in[1];
    const int*   il     = (const int*)d_in[2];
    const int*   ll     = (const int*)d_in[3];
    float* out = (float*)d_out;

    hipMemsetAsync(out, 0, sizeof(float), stream);   // d_out re-poisoned each replay
    ctc_gather<<<dim3(B_ * T_ / 4), dim3(256), 0, stream>>>(lp, labels);
    ctc_dp<<<dim3(B_), dim3(64), 0, stream>>>(lp, labels, il, ll, out);
}

// Round 4
// 365.331 us; speedup vs baseline: 1.1231x; 1.1231x over previous
//
#include <hip/hip_runtime.h>

// CTC forward loss (sum, zero_infinity), B=32, T=1024, V=1024, L=256, S=513.
//
// Pass 1 (ctc_gather, parallel): per (b,t) row, gather the 257 needed probs
//   (labels + blank), exponentiate, write labels compacted in-place into
//   cols 0..255 and the blank prob into blanks[b*T+t] (d_ws).
//
// Pass 2 (ctc_dp, sequential): one wave per batch item. States in registers
//   (lane l: states 8l..8l+7; lane 63 also state 512). Emissions staged
//   chunk-by-chunk (16 steps) into LDS via global_load_lds, double-buffered,
//   drained with explicit s_waitcnt vmcnt(16) — NO barrier in the loop, so
//   chunk k+1's loads stay in flight while chunk k computes. No big VGPR
//   arrays -> no scratch spill (R3's 519 cyc/step plateau was spill-bound).
//   Linear-domain DP with exact pow-2 rescale every 8 steps.

constexpr int B_ = 32, T_ = 1024, V_ = 1024, L_ = 256;
constexpr int S_ = 2 * L_ + 1;   // 513
constexpr int CH = 16;           // steps per staged chunk
constexpr int NCHUNK = 64;       // 64*16 = 1024 >= T-1 steps
constexpr float LN2F = 0.6931471805599453f;

typedef const __attribute__((address_space(1))) unsigned int* gp_t;
typedef __attribute__((address_space(3))) unsigned int* lp_t;

__global__ __launch_bounds__(256, 4) void ctc_gather(
    float* __restrict__ lp, const int* __restrict__ labels,
    float* __restrict__ blanks)
{
    const int wave = threadIdx.x >> 6;
    const int lane = threadIdx.x & 63;
    const int r = blockIdx.x * 4 + wave;       // row in [0, B*T)
    const int b = r >> 10;                     // T = 1024
    float* row = lp + (size_t)r * V_;
    const int* labb = labels + b * L_;

    const int4 e = *(const int4*)(labb + 4 * lane);
    const float v0 = row[e.x];
    const float v1 = row[e.y];
    const float v2 = row[e.z];
    const float v3 = row[e.w];
    const float vb = row[0];
    float4 q;
    q.x = __expf(v0); q.y = __expf(v1); q.z = __expf(v2); q.w = __expf(v3);
    const float qb = __expf(vb);
    __syncthreads();   // drains vmcnt(0): all loads done before in-place stores
    *(float4*)(row + 4 * lane) = q;            // cols 4l..4l+3
    if (lane == 0) blanks[r] = qb;
}

__global__ __launch_bounds__(64, 1) void ctc_dp(
    const float* __restrict__ Q, const float* __restrict__ blanks,
    const int* __restrict__ labels, const int* __restrict__ input_lens,
    const int* __restrict__ label_lens, float* __restrict__ out)
{
    __shared__ float blk[T_];                 // all blank probs, staged once
    __shared__ float buf[2][CH][256];         // double-buffered label probs
    __shared__ float Ls[S_];
    const int b    = blockIdx.x;
    const int lane = threadIdx.x;
    const float* Qb  = Q + (size_t)b * T_ * V_;
    const float* blg = blanks + b * T_;
    const int*  labb = labels + b * L_;
    const int il = input_lens[b];
    const int ll = label_lens[b];
    const int tend = il < T_ ? il : T_;

    // stage all 1024 blank probs (4 instr, 1 KB each: lane supplies +16B addr)
    #pragma unroll
    for (int i = 0; i < 4; ++i)
        __builtin_amdgcn_global_load_lds((gp_t)(blg + 256 * i + 4 * lane),
                                         (lp_t)&blk[256 * i], 16, 0, 0);
    // stage chunk 0 (rows t = 1..16) into buf[0]
    #pragma unroll
    for (int i = 0; i < CH; ++i) {
        int t = 1 + i; if (t > T_ - 1) t = T_ - 1;
        __builtin_amdgcn_global_load_lds((gp_t)(Qb + (size_t)t * V_ + 4 * lane),
                                         (lp_t)&buf[0][i][0], 16, 0, 0);
    }

    // lane l's label states: s = 8l+2m+1, label index 4l+m
    const int4 e  = *(const int4*)(labb + 4 * lane);
    const int  ep = (lane > 0) ? labb[4 * lane - 1] : -1;
    const float kf0 = ((8 * lane + 1) >= 3 && e.x != ep) ? 1.f : 0.f;
    const float kf1 = (e.y != e.x) ? 1.f : 0.f;
    const float kf2 = (e.z != e.y) ? 1.f : 0.f;
    const float kf3 = (e.w != e.z) ? 1.f : 0.f;

    float p0 = 0.f, p1 = 0.f, p2 = 0.f, p3 = 0.f, p4 = 0.f,
          p5 = 0.f, p6 = 0.f, p7 = 0.f, p8 = 0.f;
    if (lane == 0) { p0 = blg[0]; p1 = Qb[0]; }   // alpha at t=0 (linear)
    int Esc = 0;          // true alpha = stored * 2^{-Esc}
    float pm1 = 0.f;      // alpha[8l-1] entering the next step

    auto rescale = [&]() {
        float m = fmaxf(fmaxf(fmaxf(fmaxf(p0, p1), fmaxf(p2, p3)),
                              fmaxf(fmaxf(p4, p5), fmaxf(p6, p7))), p8);
        #pragma unroll
        for (int off = 32; off >= 1; off >>= 1)
            m = fmaxf(m, __shfl_xor(m, off));
        const unsigned eb = (__float_as_uint(m) >> 23) & 0xffu;
        if (eb >= 1u && eb <= 253u) {
            const float sf = __uint_as_float((254u - eb) << 23);  // exact 2^(127-eb)
            p0 *= sf; p1 *= sf; p2 *= sf; p3 *= sf; p4 *= sf;
            p5 *= sf; p6 *= sf; p7 *= sf; p8 *= sf; pm1 *= sf;
            Esc += 127 - (int)eb;
        }
    };

    for (int c = 0; c < NCHUNK; ++c) {
        const int cb = c & 1;
        if (c + 1 < NCHUNK) {
            #pragma unroll
            for (int i = 0; i < CH; ++i) {
                int t = 1 + (c + 1) * CH + i; if (t > T_ - 1) t = T_ - 1;
                __builtin_amdgcn_global_load_lds(
                    (gp_t)(Qb + (size_t)t * V_ + 4 * lane),
                    (lp_t)&buf[cb ^ 1][i][0], 16, 0, 0);
            }
            // wait for chunk c's 16 stages; chunk c+1's 16 remain in flight.
            // Safe: chunk c's stages always have >=16 ops issued after them.
            asm volatile("s_waitcnt vmcnt(16)" ::: "memory");
        } else {
            asm volatile("s_waitcnt vmcnt(0)" ::: "memory");
        }
        #pragma unroll
        for (int i = 0; i < CH; ++i) {
            const int t = 1 + c * CH + i;
            if (t < tend) {                    // wave-uniform
                const float4 q  = *(const float4*)&buf[cb][i][4 * lane];
                const float  qb = blk[t];
                const float n0 = (p0 + pm1) * qb;
                const float n1 = fmaf(kf0, pm1, p1 + p0) * q.x;
                const float n2 = (p2 + p1) * qb;
                const float n3 = fmaf(kf1, p1, p3 + p2) * q.y;
                const float n4 = (p4 + p3) * qb;
                const float n5 = fmaf(kf2, p3, p5 + p4) * q.z;
                const float n6 = (p6 + p5) * qb;
                const float n7 = fmaf(kf3, p5, p7 + p6) * q.w;
                const float n8 = (p8 + p7) * qb;  // state 8l+8 (512 on lane 63)
                p0 = n0; p1 = n1; p2 = n2; p3 = n3; p4 = n4;
                p5 = n5; p6 = n6; p7 = n7; p8 = n8;
                pm1 = __shfl_up(p7, 1);
                if (lane == 0) pm1 = 0.f;
            }
            if (i == 7) rescale();
        }
        rescale();
    }

    // epilogue: pick states 2*ll and 2*ll-1 via LDS (single wave, in-order DS)
    Ls[8 * lane + 0] = p0; Ls[8 * lane + 1] = p1;
    Ls[8 * lane + 2] = p2; Ls[8 * lane + 3] = p3;
    Ls[8 * lane + 4] = p4; Ls[8 * lane + 5] = p5;
    Ls[8 * lane + 6] = p6; Ls[8 * lane + 7] = p7;
    if (lane == 63) Ls[512] = p8;
    __syncthreads();
    if (lane == 0) {
        const int sl = 2 * ll;
        const float la  = Ls[sl];
        const float lb  = (sl >= 1) ? Ls[sl - 1] : 0.f;
        const float tot = la + lb;
        float loss = (float)Esc * LN2F - __logf(tot);
        if (!(loss <= 1e29f)) loss = 0.f;     // zero_infinity
        atomicAdd(out, loss);
    }
}

extern "C" void kernel_launch(void* const* d_in, const int* in_sizes, int n_in,
                              void* d_out, int out_size, void* d_ws, size_t ws_size,
                              hipStream_t stream) {
    float*       lp     = (float*)d_in[0];    // mutated by pass 1; restored each replay
    const int*   labels = (const int*)d_in[1];
    const int*   il     = (const int*)d_in[2];
    const int*   ll     = (const int*)d_in[3];
    float* out    = (float*)d_out;
    float* blanks = (float*)d_ws;             // B*T floats = 128 KB scratch

    hipMemsetAsync(out, 0, sizeof(float), stream);   // d_out re-poisoned each replay
    ctc_gather<<<dim3(B_ * T_ / 4), dim3(256), 0, stream>>>(lp, labels, blanks);
    ctc_dp<<<dim3(B_), dim3(64), 0, stream>>>(lp, blanks, labels, il, ll, out);
}

// Round 5
// 340.802 us; speedup vs baseline: 1.2039x; 1.0720x over previous
//
#include <hip/hip_runtime.h>

// CTC forward loss (sum, zero_infinity), B=32, T=1024, V=1024, L=256, S=513.
//
// Pass 1 (ctc_gather): per (b,t) row, gather the 257 needed probs, exp(),
//   write labels compacted in-place (cols 0..255) and blank into d_ws.
//
// Pass 2 (ctc_dp): one wave per batch item, states in registers
//   (lane l: states 8l..8l+7; lane 63 also state 512). Emissions prefetched
//   into a register TRIPLE buffer (3 chunks x 8 steps x float4), each load
//   block bracketed by sched_barrier(0) so the scheduler can't sink the
//   loads to their uses (R3's failure) — and no in-loop global_load_lds, so
//   the backend never emits a conservative vmcnt(0) before ds_reads (R4's
//   failure). Blanks staged to LDS once pre-loop; per-step broadcast read.
//   Linear-domain DP with exact pow-2 rescale every 8 steps.

constexpr int B_ = 32, T_ = 1024, V_ = 1024, L_ = 256;
constexpr int S_ = 2 * L_ + 1;   // 513
constexpr float LN2F = 0.6931471805599453f;

typedef const __attribute__((address_space(1))) unsigned int* gp_t;
typedef __attribute__((address_space(3))) unsigned int* lp_t;

__global__ __launch_bounds__(256, 4) void ctc_gather(
    float* __restrict__ lp, const int* __restrict__ labels,
    float* __restrict__ blanks)
{
    const int wave = threadIdx.x >> 6;
    const int lane = threadIdx.x & 63;
    const int r = blockIdx.x * 4 + wave;       // row in [0, B*T)
    const int b = r >> 10;                     // T = 1024
    float* row = lp + (size_t)r * V_;
    const int* labb = labels + b * L_;

    const int4 e = *(const int4*)(labb + 4 * lane);
    const float v0 = row[e.x];
    const float v1 = row[e.y];
    const float v2 = row[e.z];
    const float v3 = row[e.w];
    const float vb = row[0];
    float4 q;
    q.x = __expf(v0); q.y = __expf(v1); q.z = __expf(v2); q.w = __expf(v3);
    const float qb = __expf(vb);
    __syncthreads();   // vmcnt(0) drain: all loads done before in-place stores
    *(float4*)(row + 4 * lane) = q;            // cols 4l..4l+3
    if (lane == 0) blanks[r] = qb;
}

__global__ __launch_bounds__(64, 1) void ctc_dp(
    const float* __restrict__ Q, const float* __restrict__ blanks,
    const int* __restrict__ labels, const int* __restrict__ input_lens,
    const int* __restrict__ label_lens, float* __restrict__ out)
{
    __shared__ float blk[T_];                  // blank probs, staged once
    __shared__ float Ls[S_];
    const int b    = blockIdx.x;
    const int lane = threadIdx.x;
    const float* Qb  = Q + (size_t)b * T_ * V_;
    const float* blg = blanks + b * T_;
    const int*  labb = labels + b * L_;
    const int il = input_lens[b];
    const int ll = label_lens[b];
    const int tend = il < T_ ? il : T_;

    // stage all 1024 blank probs into LDS (only LDS-writing VM ops in the
    // kernel; drained once by the compiler before the first ds_read).
    #pragma unroll
    for (int i = 0; i < 4; ++i)
        __builtin_amdgcn_global_load_lds((gp_t)(blg + 256 * i + 4 * lane),
                                         (lp_t)&blk[256 * i], 16, 0, 0);

    // lane l's label states: s = 8l+2m+1, label index 4l+m
    const int4 e  = *(const int4*)(labb + 4 * lane);
    const int  ep = (lane > 0) ? labb[4 * lane - 1] : -1;
    const float kf0 = ((8 * lane + 1) >= 3 && e.x != ep) ? 1.f : 0.f;
    const float kf1 = (e.y != e.x) ? 1.f : 0.f;
    const float kf2 = (e.z != e.y) ? 1.f : 0.f;
    const float kf3 = (e.w != e.z) ? 1.f : 0.f;

    float p0 = 0.f, p1 = 0.f, p2 = 0.f, p3 = 0.f, p4 = 0.f,
          p5 = 0.f, p6 = 0.f, p7 = 0.f, p8 = 0.f;
    if (lane == 0) { p0 = blg[0]; p1 = Qb[0]; }   // alpha at t=0 (linear)
    int Esc = 0;          // true alpha = stored * 2^{-Esc}
    float pm1 = 0.f;      // alpha[8l-1] entering the next step

    float4 bufA[8], bufB[8], bufC[8];      // register triple buffer

// Load one chunk (8 rows x float4/lane). sched_barrier(0) on BOTH sides:
// loads can't sink to uses, and can't hoist over the previous consumer
// of the same buffer (bounds register pressure / prevents renaming).
#define ISSUE(c, BUF)                                                        \
    do {                                                                     \
        __builtin_amdgcn_sched_barrier(0);                                   \
        _Pragma("unroll")                                                    \
        for (int ii = 0; ii < 8; ++ii) {                                     \
            int tt = 1 + (c) * 8 + ii;                                       \
            if (tt > T_ - 1) tt = T_ - 1;                                    \
            BUF[ii] = *(const float4*)(Qb + (size_t)tt * V_ + 4 * lane);     \
        }                                                                    \
        __builtin_amdgcn_sched_barrier(0);                                   \
    } while (0)

    auto rescale = [&]() {
        float m = fmaxf(fmaxf(fmaxf(fmaxf(p0, p1), fmaxf(p2, p3)),
                              fmaxf(fmaxf(p4, p5), fmaxf(p6, p7))), p8);
        #pragma unroll
        for (int off = 32; off >= 1; off >>= 1)
            m = fmaxf(m, __shfl_xor(m, off));
        const unsigned eb = (__float_as_uint(m) >> 23) & 0xffu;
        if (eb >= 1u && eb <= 253u) {
            const float sf = __uint_as_float((254u - eb) << 23);  // exact 2^(127-eb)
            p0 *= sf; p1 *= sf; p2 *= sf; p3 *= sf; p4 *= sf;
            p5 *= sf; p6 *= sf; p7 *= sf; p8 *= sf; pm1 *= sf;
            Esc += 127 - (int)eb;
        }
    };

#define COMPUTE(c, BUF)                                                      \
    do {                                                                     \
        _Pragma("unroll")                                                    \
        for (int ii = 0; ii < 8; ++ii) {                                     \
            const int t = 1 + (c) * 8 + ii;                                  \
            if (t < tend) {        /* wave-uniform scalar branch */          \
                const float4 q  = BUF[ii];                                   \
                const float  qb = blk[t];        /* broadcast ds_read */     \
                const float n0 = (p0 + pm1) * qb;                            \
                const float n1 = fmaf(kf0, pm1, p1 + p0) * q.x;              \
                const float n2 = (p2 + p1) * qb;                             \
                const float n3 = fmaf(kf1, p1, p3 + p2) * q.y;               \
                const float n4 = (p4 + p3) * qb;                             \
                const float n5 = fmaf(kf2, p3, p5 + p4) * q.z;               \
                const float n6 = (p6 + p5) * qb;                             \
                const float n7 = fmaf(kf3, p5, p7 + p6) * q.w;               \
                const float n8 = (p8 + p7) * qb;  /* state 8l+8 (512@63) */  \
                p0 = n0; p1 = n1; p2 = n2; p3 = n3; p4 = n4;                 \
                p5 = n5; p6 = n6; p7 = n7; p8 = n8;                          \
                pm1 = __shfl_up(p7, 1);                                      \
                if (lane == 0) pm1 = 0.f;                                    \
            }                                                                \
        }                                                                    \
        rescale();                                                           \
    } while (0)

    ISSUE(0, bufA);
    ISSUE(1, bufB);
    // 129 chunks of 8 steps cover t = 1..1032 (t >= tend guarded off;
    // out-of-range prefetch rows clamp to row T-1 — harmless duplicates).
    for (int c = 0; c < 129; c += 3) {
        ISSUE(c + 2, bufC);
        COMPUTE(c, bufA);
        ISSUE(c + 3, bufA);
        COMPUTE(c + 1, bufB);
        ISSUE(c + 4, bufB);
        COMPUTE(c + 2, bufC);
    }
#undef ISSUE
#undef COMPUTE

    // epilogue: pick states 2*ll and 2*ll-1 via LDS
    Ls[8 * lane + 0] = p0; Ls[8 * lane + 1] = p1;
    Ls[8 * lane + 2] = p2; Ls[8 * lane + 3] = p3;
    Ls[8 * lane + 4] = p4; Ls[8 * lane + 5] = p5;
    Ls[8 * lane + 6] = p6; Ls[8 * lane + 7] = p7;
    if (lane == 63) Ls[512] = p8;
    __syncthreads();
    if (lane == 0) {
        const int sl = 2 * ll;
        const float la  = Ls[sl];
        const float lb  = (sl >= 1) ? Ls[sl - 1] : 0.f;
        const float tot = la + lb;
        float loss = (float)Esc * LN2F - __logf(tot);
        if (!(loss <= 1e29f)) loss = 0.f;     // zero_infinity
        atomicAdd(out, loss);
    }
}

extern "C" void kernel_launch(void* const* d_in, const int* in_sizes, int n_in,
                              void* d_out, int out_size, void* d_ws, size_t ws_size,
                              hipStream_t stream) {
    float*       lp     = (float*)d_in[0];    // mutated by pass 1; restored each replay
    const int*   labels = (const int*)d_in[1];
    const int*   il     = (const int*)d_in[2];
    const int*   ll     = (const int*)d_in[3];
    float* out    = (float*)d_out;
    float* blanks = (float*)d_ws;             // B*T floats = 128 KB scratch

    hipMemsetAsync(out, 0, sizeof(float), stream);   // d_out re-poisoned each replay
    ctc_gather<<<dim3(B_ * T_ / 4), dim3(256), 0, stream>>>(lp, labels, blanks);
    ctc_dp<<<dim3(B_), dim3(64), 0, stream>>>(lp, blanks, labels, il, ll, out);
}